// Round 1
// baseline (38952.017 us; speedup 1.0000x reference)
//
#include <hip/hip_runtime.h>
#include <cstdint>
#include <cstddef>

// Problem constants
#define BB 32
#define TT 1024
#define DD 512
#define HH 512
#define NBLK 256           // persistent blocks: 128 per direction

typedef __bf16 bf16x8 __attribute__((ext_vector_type(8)));
typedef float  f32x4  __attribute__((ext_vector_type(4)));

// ws layout (bytes):
//   hfrag  : ushort[2 dir][2 buf][2 ntile][16 s][64 lane][8]  = 65536 us = 131072 B @ 0
//   xhat   : float [2 pass][TT][BB]                            = 262144 B @ 131072
//   flags  : int   [NBLK*16]                                   =  16384 B @ 393216
//   gen    : int                                               @ 409600
#define HFRAG_OFF 0
#define XHAT_OFF  131072
#define FLAGS_OFF 393216
#define GEN_OFF   409600

__device__ __forceinline__ float sigm(float x) {
    return 1.f / (1.f + __expf(-x));
}
__device__ __forceinline__ float tanh_fast(float x) {
    x = fminf(15.f, fmaxf(-15.f, x));
    float e = __expf(2.f * x);
    return (e - 1.f) / (e + 1.f);
}

__device__ __forceinline__ void gbarrier(int* flags, int* gen, int phase, int bid) {
    __syncthreads();  // all waves' stores drained to L2 (vmcnt 0)
    if (threadIdx.x == 0) {
        __threadfence();  // release: flush dirty L2 to coherence point
        __hip_atomic_store(&flags[bid * 16], phase, __ATOMIC_RELAXED, __HIP_MEMORY_SCOPE_AGENT);
    }
    if (bid == 0) {
        for (int i = threadIdx.x; i < NBLK; i += 128) {
            while (__hip_atomic_load(&flags[i * 16], __ATOMIC_RELAXED, __HIP_MEMORY_SCOPE_AGENT) != phase)
                __builtin_amdgcn_s_sleep(1);
        }
        __syncthreads();
        if (threadIdx.x == 0)
            __hip_atomic_store(gen, phase, __ATOMIC_RELAXED, __HIP_MEMORY_SCOPE_AGENT);
    } else {
        if (threadIdx.x == 0) {
            while (__hip_atomic_load(gen, __ATOMIC_RELAXED, __HIP_MEMORY_SCOPE_AGENT) != phase)
                __builtin_amdgcn_s_sleep(1);
        }
    }
    __syncthreads();
    __threadfence();  // acquire: invalidate caches before reading peers' h
}

__global__ __launch_bounds__(128, 1) void lstm_persistent(
    const float* __restrict__ u,
    const float* __restrict__ wih_f, const float* __restrict__ whh_f,
    const float* __restrict__ bih_f, const float* __restrict__ bhh_f,
    const float* __restrict__ wih_b, const float* __restrict__ whh_b,
    const float* __restrict__ bih_b, const float* __restrict__ bhh_b,
    unsigned short* __restrict__ hfrag, float* __restrict__ xhat,
    int* __restrict__ flags, int* __restrict__ gen)
{
    const int bid  = blockIdx.x;
    const int dir  = bid >> 7;        // 0 = forward cell, 1 = backward cell
    const int kb   = bid & 127;
    const int k0   = kb << 2;         // 4 hidden columns per block
    const int tid  = threadIdx.x;
    const int wid  = tid >> 6;        // batch-half (N-tile) this wave owns
    const int lane = tid & 63;
    const int quad = lane >> 4;
    const int l16  = lane & 15;

    const float* wih = dir ? wih_b : wih_f;
    const float* whh = dir ? whh_b : whh_f;
    const float* bih = dir ? bih_b : bih_f;
    const float* bhh = dir ? bhh_b : bhh_f;

    // ---- A-fragments (weights) pinned in registers for the whole kernel ----
    // M-tile rows: j_local = gate*4 + kk  -> global row j = gate*H + k0 + kk
    // A-frag layout: lane holds A[m = lane&15][k = quad*8 + i], i = 0..7
    bf16x8 wihF[16], whhF[16];
    {
        const int jg = (l16 >> 2) * HH + k0 + (l16 & 3);
        #pragma unroll
        for (int s = 0; s < 16; ++s) {
            const float* p = wih + (size_t)jg * DD + s * 32 + quad * 8;
            const float* q = whh + (size_t)jg * HH + s * 32 + quad * 8;
            bf16x8 a, b;
            #pragma unroll
            for (int i = 0; i < 8; ++i) { a[i] = (__bf16)p[i]; b[i] = (__bf16)q[i]; }
            wihF[s] = a;
            whhF[s] = b;
        }
    }

    // ---- per-lane cell constants: cell = (kk = quad, b = wid*16 + l16) ----
    const int kc = k0 + quad;          // this lane's hidden column
    const int bc = wid * 16 + l16;     // this lane's batch index
    float biasv[4], rsv[4];
    #pragma unroll
    for (int g = 0; g < 4; ++g) {
        const int j = g * HH + kc;
        biasv[g] = bih[j] + bhh[j];
        float s = 0.f;
        const float* row = wih + (size_t)j * DD;
        for (int d = 0; d < DD; ++d) s += row[d];
        rsv[g] = s;  // rowsum(W_ih) for the x_hat linear correction in pass 2
    }

    // ---- h write slot (B-fragment layout position for (m=kc, n=bc)) ----
    const int sw = kc >> 5, qw = (kc >> 3) & 3, iw = kc & 7;
    const int lanew = qw * 16 + l16;
    const int wslot0 = ((((dir * 2 + 0) * 2 + wid) * 16 + sw) * 64 + lanew) * 8 + iw;
    const int wslot1 = wslot0 + 2 * 16 * 64 * 8;   // buf 1 offset

    // zero-init h buffer 0 (each lane covers exactly its own slot; union = full buffer)
    hfrag[wslot0] = 0;

    __shared__ __align__(16) float gbuf[2][16][20];  // wave-private gate transpose buffers

    const uint4* hv4 = (const uint4*)hfrag;
    const int rbase = ((dir * 2) * 2 + wid) * 16 * 64 + lane;  // + bufR*(2*16*64) + s*64

    int phase = 1;
    gbarrier(flags, gen, phase, bid); ++phase;   // h0 visible everywhere

    float c = 0.f;
    f32x4 gih;

    for (int t = 0; t < TT; ++t) {
        #pragma unroll 1
        for (int pass = 0; pass < 2; ++pass) {
            const int bufR = (t * 2 + pass) & 1;
            f32x4 acc0, acc1;
            float xc;
            if (pass == 0) {
                // input-side GEMM on u_t (computed once per timestep, reused in pass 2)
                acc0 = (f32x4){0.f, 0.f, 0.f, 0.f};
                acc1 = (f32x4){0.f, 0.f, 0.f, 0.f};
                const float* ub = u + (size_t)bc * (TT * DD) + (size_t)t * DD + quad * 8;
                #pragma unroll
                for (int s = 0; s < 16; ++s) {
                    const float4* p = (const float4*)(ub + s * 32);
                    float4 a0 = p[0], a1 = p[1];
                    bf16x8 uf;
                    uf[0] = (__bf16)a0.x; uf[1] = (__bf16)a0.y;
                    uf[2] = (__bf16)a0.z; uf[3] = (__bf16)a0.w;
                    uf[4] = (__bf16)a1.x; uf[5] = (__bf16)a1.y;
                    uf[6] = (__bf16)a1.z; uf[7] = (__bf16)a1.w;
                    if (s & 1) acc1 = __builtin_amdgcn_mfma_f32_16x16x32_bf16(wihF[s], uf, acc1, 0, 0, 0);
                    else       acc0 = __builtin_amdgcn_mfma_f32_16x16x32_bf16(wihF[s], uf, acc0, 0, 0, 0);
                }
                gih = acc0 + acc1;
                acc0 = gih;
                acc1 = (f32x4){0.f, 0.f, 0.f, 0.f};
                xc = 0.f;
            } else {
                acc0 = gih;
                acc1 = (f32x4){0.f, 0.f, 0.f, 0.f};
                xc = xhat[t * BB + bc];   // pass-1 scalar feedback, exact linear correction
            }
            // recurrent GEMM: B-fragments read straight from global in frag layout
            {
                const int rb = rbase + bufR * (2 * 16 * 64);
                #pragma unroll
                for (int s = 0; s < 16; ++s) {
                    uint4 hv = hv4[rb + s * 64];
                    bf16x8 hf = __builtin_bit_cast(bf16x8, hv);
                    if (s & 1) acc1 = __builtin_amdgcn_mfma_f32_16x16x32_bf16(whhF[s], hf, acc1, 0, 0, 0);
                    else       acc0 = __builtin_amdgcn_mfma_f32_16x16x32_bf16(whhF[s], hf, acc0, 0, 0, 0);
                }
            }
            f32x4 acc = acc0 + acc1;

            // D-layout -> per-cell gates via wave-private LDS (no cross-wave sharing)
            float4 gw; gw.x = acc[0]; gw.y = acc[1]; gw.z = acc[2]; gw.w = acc[3];
            *(float4*)&gbuf[wid][l16][quad * 4] = gw;
            __syncthreads();
            float gI = gbuf[wid][l16][ 0 + quad] + biasv[0] + xc * rsv[0];
            float gF = gbuf[wid][l16][ 4 + quad] + biasv[1] + xc * rsv[1];
            float gG = gbuf[wid][l16][ 8 + quad] + biasv[2] + xc * rsv[2];
            float gO = gbuf[wid][l16][12 + quad] + biasv[3] + xc * rsv[3];

            float ig = sigm(gI), fg = sigm(gF), gg = tanh_fast(gG), og = sigm(gO);
            c = fg * c + ig * gg;
            float h = og * tanh_fast(c);

            // publish h (bf16, B-frag layout) into the buffer pass p+1 will read
            unsigned short hb = __builtin_bit_cast(unsigned short, (__bf16)h);
            hfrag[bufR ? wslot0 : wslot1] = hb;
            if (dir == 1 && kc == (HH - 1))
                xhat[pass * (TT * BB) + t * BB + bc] = h;   // fp32 scalar feedback/output

            gbarrier(flags, gen, phase, bid); ++phase;
        }
    }
}

__global__ void epilogue(const float* __restrict__ u, const float* __restrict__ xhat,
                         float* __restrict__ out)
{
    const int i = blockIdx.x * blockDim.x + threadIdx.x;   // over float4 groups
    const float4 uv = ((const float4*)u)[i];
    const int bt = i >> 7;             // 128 float4 per (b,t)
    const int t = bt & (TT - 1);
    const int b = bt >> 10;
    const float s = 0.5f * (xhat[t * BB + b] + xhat[TT * BB + t * BB + b]);
    float4 o;
    o.x = 1.5f * uv.x + s;
    o.y = 1.5f * uv.y + s;
    o.z = 1.5f * uv.z + s;
    o.w = 1.5f * uv.w + s;
    ((float4*)out)[i] = o;
}

extern "C" void kernel_launch(void* const* d_in, const int* in_sizes, int n_in,
                              void* d_out, int out_size, void* d_ws, size_t ws_size,
                              hipStream_t stream) {
    const float* u     = (const float*)d_in[0];
    const float* wih_f = (const float*)d_in[1];
    const float* whh_f = (const float*)d_in[2];
    const float* bih_f = (const float*)d_in[3];
    const float* bhh_f = (const float*)d_in[4];
    const float* wih_b = (const float*)d_in[5];
    const float* whh_b = (const float*)d_in[6];
    const float* bih_b = (const float*)d_in[7];
    const float* bhh_b = (const float*)d_in[8];

    char* ws = (char*)d_ws;
    unsigned short* hfrag = (unsigned short*)(ws + HFRAG_OFF);
    float* xhat           = (float*)(ws + XHAT_OFF);
    int* flags            = (int*)(ws + FLAGS_OFF);
    int* gen              = (int*)(ws + GEN_OFF);

    lstm_persistent<<<NBLK, 128, 0, stream>>>(
        u, wih_f, whh_f, bih_f, bhh_f, wih_b, whh_b, bih_b, bhh_b,
        hfrag, xhat, flags, gen);

    const int n4 = BB * TT * DD / 4;
    epilogue<<<n4 / 256, 256, 0, stream>>>(u, xhat, (float*)d_out);
}

// Round 3
// 21615.132 us; speedup vs baseline: 1.8021x; 1.8021x over previous
//
#include <hip/hip_runtime.h>
#include <cstdint>
#include <cstddef>

// Problem constants
#define BB 32
#define TT 1024
#define DD 512
#define HH 512
#define NBLK 256           // persistent blocks: 128 per direction

typedef __bf16 bf16x8 __attribute__((ext_vector_type(8)));
typedef float  f32x4  __attribute__((ext_vector_type(4)));
typedef unsigned long long u64;

// ws layout (bytes):
//   hfrag  : ushort[2 dir][2 buf][2 ntile][16 s][64 lane][8]  = 65536 us = 131072 B @ 0
//   xhat   : float [2 pass][TT][BB]                            = 262144 B @ 131072
//   flags  : int   [NBLK]                                      =   1024 B @ 393216
#define HFRAG_OFF 0
#define XHAT_OFF  131072
#define FLAGS_OFF 393216

#define AT_LOAD(p)     __hip_atomic_load((p),      __ATOMIC_RELAXED, __HIP_MEMORY_SCOPE_AGENT)
#define AT_STORE(p, v) __hip_atomic_store((p), (v), __ATOMIC_RELAXED, __HIP_MEMORY_SCOPE_AGENT)

__device__ __forceinline__ float sigm(float x) {
    return 1.f / (1.f + __expf(-x));
}
__device__ __forceinline__ float tanh_fast(float x) {
    x = fminf(15.f, fmaxf(-15.f, x));
    float e = __expf(2.f * x);
    return (e - 1.f) / (e + 1.f);
}

// Split barrier over a MONOTONE phase counter.
// arrive: drain this block's sc1 data stores, then release-publish flag=phase.
// waitall: every block polls all 256 flags for flag >= phase (signed: the
// 0xAAAAAAAA ws-poison is negative, so un-launched blocks read as "not yet").
// '>=' (not '==') makes the poll immune to a fast block overwriting its flag
// with phase+1 before a straggler observes phase — the R2 deadlock.
__device__ __forceinline__ void arrive(int* flags, int phase, int bid) {
    __builtin_amdgcn_s_waitcnt(0);   // per-wave: h/xhat sc1 stores reached LLC
    __syncthreads();                 // both waves drained
    if (threadIdx.x == 0)
        __hip_atomic_store(&flags[bid], phase, __ATOMIC_RELEASE, __HIP_MEMORY_SCOPE_AGENT);
}

__device__ __forceinline__ void waitall(const int* flags, int phase) {
    if (threadIdx.x < 64) {
        const u64* f64 = (const u64*)flags;
        const int i = threadIdx.x * 2;           // lane covers flags[4L..4L+3]
        for (;;) {
            u64 a = AT_LOAD(&f64[i]);
            u64 b = AT_LOAD(&f64[i + 1]);
            int a0 = (int)a, a1 = (int)(a >> 32);
            int b0 = (int)b, b1 = (int)(b >> 32);
            bool ok = (a0 >= phase) & (a1 >= phase) & (b0 >= phase) & (b1 >= phase);
            if (__all(ok)) break;
            __builtin_amdgcn_s_sleep(1);
        }
    }
    __syncthreads();
}

__global__ __launch_bounds__(128, 1) void lstm_persistent(
    const float* __restrict__ u,
    const float* __restrict__ wih_f, const float* __restrict__ whh_f,
    const float* __restrict__ bih_f, const float* __restrict__ bhh_f,
    const float* __restrict__ wih_b, const float* __restrict__ whh_b,
    const float* __restrict__ bih_b, const float* __restrict__ bhh_b,
    unsigned short* __restrict__ hfrag, float* __restrict__ xhat,
    int* __restrict__ flags)
{
    const int bid  = blockIdx.x;
    const int dir  = bid >> 7;        // 0 = forward cell, 1 = backward cell
    const int kb   = bid & 127;
    const int k0   = kb << 2;         // 4 hidden columns per block
    const int tid  = threadIdx.x;
    const int wid  = tid >> 6;        // batch-half (N-tile) this wave owns
    const int lane = tid & 63;
    const int quad = lane >> 4;
    const int l16  = lane & 15;

    const float* wih = dir ? wih_b : wih_f;
    const float* whh = dir ? whh_b : whh_f;
    const float* bih = dir ? bih_b : bih_f;
    const float* bhh = dir ? bhh_b : bhh_f;

    // ---- A-fragments (weights) pinned in registers for the whole kernel ----
    // A-frag layout: lane holds A[m = lane&15][k = quad*8 + i], i = 0..7
    // M rows: m -> global gate row j = (m>>2)*HH + k0 + (m&3)
    bf16x8 wihF[16], whhF[16];
    {
        const int jg = (l16 >> 2) * HH + k0 + (l16 & 3);
        #pragma unroll
        for (int s = 0; s < 16; ++s) {
            const float* p = wih + (size_t)jg * DD + s * 32 + quad * 8;
            const float* q = whh + (size_t)jg * HH + s * 32 + quad * 8;
            bf16x8 a, b;
            #pragma unroll
            for (int i = 0; i < 8; ++i) { a[i] = (__bf16)p[i]; b[i] = (__bf16)q[i]; }
            wihF[s] = a;
            whhF[s] = b;
        }
    }

    // ---- per-lane cell constants: cell = (kk = quad, b = wid*16 + l16) ----
    const int kc = k0 + quad;          // this lane's hidden column
    const int bc = wid * 16 + l16;     // this lane's batch index

    // rowsum(W_ih) from the frags (bf16-rounded terms == what the MFMA uses)
    float rsv[4], biasv[4];
    {
        float rs = 0.f;
        #pragma unroll
        for (int s = 0; s < 16; ++s)
            #pragma unroll
            for (int i = 0; i < 8; ++i) rs += (float)wihF[s][i];
        rs += __shfl_xor(rs, 16);
        rs += __shfl_xor(rs, 32);      // lane l16 holds rowsum of row j(l16)
        #pragma unroll
        for (int g = 0; g < 4; ++g) {
            rsv[g]   = __shfl(rs, g * 4 + quad);   // row j = g*HH + kc
            const int j = g * HH + kc;
            biasv[g] = bih[j] + bhh[j];
        }
    }

    // ---- h slot addressing (B-fragment layout position for (m=kc, n=bc)) ----
    // ushort idx = ((((dir*2+buf)*2+wid)*16 + s)*64 + lane)*8 + i
    const int sw = kc >> 5, qw = (kc >> 3) & 3, iw = kc & 7;
    const int lanew = qw * 16 + l16;
    unsigned* hfrag32 = (unsigned*)hfrag;
    const int ws32_0 = (((((dir * 2 + 0) * 2 + wid) * 16 + sw) * 64 + lanew) * 8 + iw) >> 1;
    const int ws32_1 = ws32_0 + (2 * 16 * 64 * 8 >> 1);
    const u64* h64 = (const u64*)hfrag;
    const int rbA = ((dir * 2 + 0) * 2 + wid) * 2048 + lane * 2;   // buf0, u64 units
    const int rbB = ((dir * 2 + 1) * 2 + wid) * 2048 + lane * 2;   // buf1

    // zero-init h buffer 0 (quad-even lanes cover all packed pairs)
    if (!(quad & 1)) AT_STORE(&hfrag32[ws32_0], 0u);

    __shared__ __align__(16) float gbuf[2][16][20];  // wave-private gate transpose

    // input-side GEMM on u_t (plain cached loads; overlapped with barrier settle)
    auto ugemm = [&](int t) -> f32x4 {
        f32x4 a0 = (f32x4){0.f, 0.f, 0.f, 0.f};
        f32x4 a1 = (f32x4){0.f, 0.f, 0.f, 0.f};
        const float* ub = u + (size_t)bc * (TT * DD) + (size_t)t * DD + quad * 8;
        #pragma unroll
        for (int s = 0; s < 16; ++s) {
            const float4* p = (const float4*)(ub + s * 32);
            float4 x0 = p[0], x1 = p[1];
            bf16x8 uf;
            uf[0] = (__bf16)x0.x; uf[1] = (__bf16)x0.y;
            uf[2] = (__bf16)x0.z; uf[3] = (__bf16)x0.w;
            uf[4] = (__bf16)x1.x; uf[5] = (__bf16)x1.y;
            uf[6] = (__bf16)x1.z; uf[7] = (__bf16)x1.w;
            if (s & 1) a1 = __builtin_amdgcn_mfma_f32_16x16x32_bf16(wihF[s], uf, a1, 0, 0, 0);
            else       a0 = __builtin_amdgcn_mfma_f32_16x16x32_bf16(wihF[s], uf, a0, 0, 0, 0);
        }
        return a0 + a1;
    };

    arrive(flags, 1, bid);
    f32x4 gih = ugemm(0);          // t=0 input GEMM hides in the init barrier
    waitall(flags, 1);
    int phase = 2;

    float c = 0.f;
    f32x4 gnext = gih;

    for (int t = 0; t < TT; ++t) {
        #pragma unroll 1
        for (int pass = 0; pass < 2; ++pass) {
            const int bufR = (t * 2 + pass) & 1;
            float xc = 0.f;
            if (pass) xc = AT_LOAD(&xhat[t * BB + bc]);  // pass-1 scalar feedback

            // recurrent GEMM: prefetch all B-fragments (sc1 -> LLC), then MFMA
            u64 ha[16], hb[16];
            {
                const int rb = bufR ? rbB : rbA;
                #pragma unroll
                for (int s = 0; s < 16; ++s) {
                    ha[s] = AT_LOAD(&h64[rb + s * 128]);
                    hb[s] = AT_LOAD(&h64[rb + s * 128 + 1]);
                }
            }
            f32x4 acc0 = gih;
            f32x4 acc1 = (f32x4){0.f, 0.f, 0.f, 0.f};
            #pragma unroll
            for (int s = 0; s < 16; ++s) {
                union { u64 q[2]; bf16x8 v; } cvt;
                cvt.q[0] = ha[s]; cvt.q[1] = hb[s];
                if (s & 1) acc1 = __builtin_amdgcn_mfma_f32_16x16x32_bf16(whhF[s], cvt.v, acc1, 0, 0, 0);
                else       acc0 = __builtin_amdgcn_mfma_f32_16x16x32_bf16(whhF[s], cvt.v, acc0, 0, 0, 0);
            }
            f32x4 acc = acc0 + acc1;

            // D-layout -> per-cell gates via wave-private LDS
            float4 gw; gw.x = acc[0]; gw.y = acc[1]; gw.z = acc[2]; gw.w = acc[3];
            *(float4*)&gbuf[wid][l16][quad * 4] = gw;
            __syncthreads();
            float gI = gbuf[wid][l16][ 0 + quad] + biasv[0] + xc * rsv[0];
            float gF = gbuf[wid][l16][ 4 + quad] + biasv[1] + xc * rsv[1];
            float gG = gbuf[wid][l16][ 8 + quad] + biasv[2] + xc * rsv[2];
            float gO = gbuf[wid][l16][12 + quad] + biasv[3] + xc * rsv[3];

            float ig = sigm(gI), fg = sigm(gF), gg = tanh_fast(gG), og = sigm(gO);
            c = fg * c + ig * gg;
            float h = og * tanh_fast(c);

            // publish h: pack 2 bf16 (quad pair) -> one u32 sc1 store into buf 1-bufR
            float hp = __shfl_xor(h, 16);
            if (!(quad & 1)) {
                unsigned lo = (unsigned)__builtin_bit_cast(unsigned short, (__bf16)h);
                unsigned hi = (unsigned)__builtin_bit_cast(unsigned short, (__bf16)hp);
                AT_STORE(&hfrag32[bufR ? ws32_0 : ws32_1], lo | (hi << 16));
            }
            if (dir == 1 && kc == (HH - 1))
                AT_STORE(&xhat[pass * (TT * BB) + t * BB + bc], h);  // fp32 feedback/output

            arrive(flags, phase, bid);
            if (pass == 1 && t + 1 < TT)
                gnext = ugemm(t + 1);     // next timestep's input GEMM hides here
            waitall(flags, phase); ++phase;
        }
        gih = gnext;
    }
}

__global__ void epilogue(const float* __restrict__ u, const float* __restrict__ xhat,
                         float* __restrict__ out)
{
    const int i = blockIdx.x * blockDim.x + threadIdx.x;   // over float4 groups
    const float4 uv = ((const float4*)u)[i];
    const int bt = i >> 7;             // 128 float4 per (b,t)
    const int t = bt & (TT - 1);
    const int b = bt >> 10;
    const float s = 0.5f * (xhat[t * BB + b] + xhat[TT * BB + t * BB + b]);
    float4 o;
    o.x = 1.5f * uv.x + s;
    o.y = 1.5f * uv.y + s;
    o.z = 1.5f * uv.z + s;
    o.w = 1.5f * uv.w + s;
    ((float4*)out)[i] = o;
}

extern "C" void kernel_launch(void* const* d_in, const int* in_sizes, int n_in,
                              void* d_out, int out_size, void* d_ws, size_t ws_size,
                              hipStream_t stream) {
    const float* u     = (const float*)d_in[0];
    const float* wih_f = (const float*)d_in[1];
    const float* whh_f = (const float*)d_in[2];
    const float* bih_f = (const float*)d_in[3];
    const float* bhh_f = (const float*)d_in[4];
    const float* wih_b = (const float*)d_in[5];
    const float* whh_b = (const float*)d_in[6];
    const float* bih_b = (const float*)d_in[7];
    const float* bhh_b = (const float*)d_in[8];

    char* ws = (char*)d_ws;
    unsigned short* hfrag = (unsigned short*)(ws + HFRAG_OFF);
    float* xhat           = (float*)(ws + XHAT_OFF);
    int* flags            = (int*)(ws + FLAGS_OFF);

    lstm_persistent<<<NBLK, 128, 0, stream>>>(
        u, wih_f, whh_f, bih_f, bhh_f, wih_b, whh_b, bih_b, bhh_b,
        hfrag, xhat, flags);

    const int n4 = BB * TT * DD / 4;
    epilogue<<<n4 / 256, 256, 0, stream>>>(u, xhat, (float*)d_out);
}

// Round 4
// 15503.543 us; speedup vs baseline: 2.5125x; 1.3942x over previous
//
#include <hip/hip_runtime.h>
#include <cstdint>
#include <cstddef>

// Problem constants
#define BB 32
#define TT 1024
#define DD 512
#define HH 512
#define NBLK 128           // persistent blocks: 64 per direction, 8 cols each

typedef __bf16 bf16x8 __attribute__((ext_vector_type(8)));
typedef float  f32x4  __attribute__((ext_vector_type(4)));
typedef unsigned long long u64;

// ws layout (bytes):
//   hfrag  : ushort[2 dir][2 buf][2 ntile][16 s][64 lane][8]  = 65536 us = 131072 B @ 0
//   xhat   : float [2 pass][TT][BB]                            = 262144 B @ 131072
//   iflags : int   [NBLK]                                      =    512 B @ 393216
//   gcnt   : int   [8 groups * 16 stride]                      =    512 B @ 394240
#define HFRAG_OFF 0
#define XHAT_OFF  131072
#define IFLAG_OFF 393216
#define GCNT_OFF  394240

#define AT_LOAD(p)     __hip_atomic_load((p),      __ATOMIC_RELAXED, __HIP_MEMORY_SCOPE_AGENT)
#define AT_STORE(p, v) __hip_atomic_store((p), (v), __ATOMIC_RELAXED, __HIP_MEMORY_SCOPE_AGENT)

__device__ __forceinline__ float sigm(float x) {
    return 1.f / (1.f + __expf(-x));
}
__device__ __forceinline__ float tanh_fast(float x) {
    x = fminf(15.f, fmaxf(-15.f, x));
    float e = __expf(2.f * x);
    return (e - 1.f) / (e + 1.f);
}

// ---- barrier primitives ------------------------------------------------
// All cross-block data moves via relaxed agent-scope (sc1) atomics that
// complete at the LLC. Ordering data->flag is by COMPLETION (s_waitcnt(0)
// before the flag/counter publish), so the publish itself is RELAXED —
// no release fence, no buffer_wbl2 L2 writeback on the critical path.

// init barrier: per-block flag, poisoned-safe signed '>=' poll.
__device__ __forceinline__ void arrive_flag(int* iflags, int bid) {
    __builtin_amdgcn_s_waitcnt(0);
    __syncthreads();
    if (threadIdx.x == 0) AT_STORE(&iflags[bid], 1);
}
__device__ __forceinline__ void wait_flag(const int* iflags) {
    if (threadIdx.x < 64) {
        const u64* f64 = (const u64*)iflags;
        for (;;) {
            u64 a = AT_LOAD(&f64[threadIdx.x]);
            bool ok = ((int)a >= 1) & ((int)(a >> 32) >= 1);
            if (__all(ok)) break;
            __builtin_amdgcn_s_sleep(1);
        }
    }
    __syncthreads();
}

// main barrier: 8 group counters (64 B apart), monotone. Barrier n complete
// when every counter >= 16*n (16 blocks per group, one add per block per n).
// Max skew 1 step, same invariant the double-buffered hfrag relies on.
__device__ __forceinline__ void arrive_cnt(int* gcnt, int bid) {
    __builtin_amdgcn_s_waitcnt(0);   // h/xhat sc1 stores have reached the LLC
    __syncthreads();
    if (threadIdx.x == 0)
        __hip_atomic_fetch_add(&gcnt[(bid & 7) * 16], 1,
                               __ATOMIC_RELAXED, __HIP_MEMORY_SCOPE_AGENT);
}
__device__ __forceinline__ void wait_cnt(const int* gcnt, int target) {
    if (threadIdx.x < 64) {
        const int* p = &gcnt[(threadIdx.x & 7) * 16];
        for (;;) {
            int v = AT_LOAD(p);
            if (__all(v >= target)) break;
        }
    }
    __syncthreads();
}

__global__ __launch_bounds__(256, 1) void lstm_persistent(
    const float* __restrict__ u,
    const float* __restrict__ wih_f, const float* __restrict__ whh_f,
    const float* __restrict__ bih_f, const float* __restrict__ bhh_f,
    const float* __restrict__ wih_b, const float* __restrict__ whh_b,
    const float* __restrict__ bih_b, const float* __restrict__ bhh_b,
    unsigned short* __restrict__ hfrag, float* __restrict__ xhat,
    int* __restrict__ iflags, int* __restrict__ gcnt)
{
    const int bid  = blockIdx.x;
    const int dir  = bid >> 6;        // 0 = forward cell, 1 = backward cell
    const int kb   = bid & 63;
    const int k0   = kb << 3;         // 8 hidden columns per block
    const int tid  = threadIdx.x;
    const int wid  = tid >> 6;        // 4 waves: (mi = wid>>1, ni = wid&1)
    const int mi   = wid >> 1;        // col-group half (4 cols each)
    const int ni   = wid & 1;         // batch half (16 batches each)
    const int lane = tid & 63;
    const int quad = lane >> 4;
    const int l16  = lane & 15;

    const float* wih = dir ? wih_b : wih_f;
    const float* whh = dir ? whh_b : whh_f;
    const float* bih = dir ? bih_b : bih_f;
    const float* bhh = dir ? bhh_b : bhh_f;

    // ---- A-fragments (weights) pinned in registers for the whole kernel ----
    // A-frag layout: lane holds A[m = lane&15][k = quad*8 + i], i = 0..7
    // wave's M rows: m -> global gate row j = (m>>2)*HH + (k0 + 4*mi) + (m&3)
    bf16x8 wihF[16], whhF[16];
    {
        const int jg = (l16 >> 2) * HH + (k0 + 4 * mi) + (l16 & 3);
        #pragma unroll
        for (int s = 0; s < 16; ++s) {
            const float* p = wih + (size_t)jg * DD + s * 32 + quad * 8;
            const float* q = whh + (size_t)jg * HH + s * 32 + quad * 8;
            bf16x8 a, b;
            #pragma unroll
            for (int i = 0; i < 8; ++i) { a[i] = (__bf16)p[i]; b[i] = (__bf16)q[i]; }
            wihF[s] = a;
            whhF[s] = b;
        }
    }

    // ---- per-lane cell: (kc = k0 + 4*mi + quad, bc = ni*16 + l16) ----
    const int kc = k0 + 4 * mi + quad;
    const int bc = ni * 16 + l16;

    // rowsum(W_ih) from the frags (bf16-rounded terms == what the MFMA uses)
    float rsv[4], biasv[4];
    {
        float rs = 0.f;
        #pragma unroll
        for (int s = 0; s < 16; ++s)
            #pragma unroll
            for (int i = 0; i < 8; ++i) rs += (float)wihF[s][i];
        rs += __shfl_xor(rs, 16);
        rs += __shfl_xor(rs, 32);      // lane l16 holds rowsum of wave row l16
        #pragma unroll
        for (int g = 0; g < 4; ++g) {
            rsv[g]   = __shfl(rs, g * 4 + quad);   // row j = g*HH + kc
            const int j = g * HH + kc;
            biasv[g] = bih[j] + bhh[j];
        }
    }

    // ---- h slot addressing (B-fragment layout position for (m=kc, n=bc)) ----
    // ushort idx = ((((dir*2+buf)*2+ni)*16 + s)*64 + lane)*8 + i
    const int sw = kc >> 5, qw = (kc >> 3) & 3, iw = kc & 7;
    const int lanew = qw * 16 + l16;
    unsigned* hfrag32 = (unsigned*)hfrag;
    const int ws32_0 = (((((dir * 2 + 0) * 2 + ni) * 16 + sw) * 64 + lanew) * 8 + iw) >> 1;
    const int ws32_1 = ws32_0 + (2 * 16 * 64 * 8 >> 1);
    const u64* h64 = (const u64*)hfrag;
    const int rbA = ((dir * 2 + 0) * 2 + ni) * 2048 + lane * 2;   // buf0, u64 units
    const int rbB = ((dir * 2 + 1) * 2 + ni) * 2048 + lane * 2;   // buf1

    // zero-init h buffer 0 (quad-even lanes of all waves cover all packed pairs)
    if (!(quad & 1)) AT_STORE(&hfrag32[ws32_0], 0u);
    // zero the 8 group counters before the init barrier releases anyone
    if (bid == 0 && tid < 8) AT_STORE(&gcnt[tid * 16], 0);

    __shared__ __align__(16) float gbuf[4][16][20];  // wave-private gate transpose

    // input-side GEMM on u_t (plain cached loads; overlapped with barrier settle)
    auto ugemm = [&](int t) -> f32x4 {
        f32x4 a0 = (f32x4){0.f, 0.f, 0.f, 0.f};
        f32x4 a1 = (f32x4){0.f, 0.f, 0.f, 0.f};
        const float* ub = u + (size_t)bc * (TT * DD) + (size_t)t * DD + quad * 8;
        #pragma unroll
        for (int s = 0; s < 16; ++s) {
            const float4* p = (const float4*)(ub + s * 32);
            float4 x0 = p[0], x1 = p[1];
            bf16x8 uf;
            uf[0] = (__bf16)x0.x; uf[1] = (__bf16)x0.y;
            uf[2] = (__bf16)x0.z; uf[3] = (__bf16)x0.w;
            uf[4] = (__bf16)x1.x; uf[5] = (__bf16)x1.y;
            uf[6] = (__bf16)x1.z; uf[7] = (__bf16)x1.w;
            if (s & 1) a1 = __builtin_amdgcn_mfma_f32_16x16x32_bf16(wihF[s], uf, a1, 0, 0, 0);
            else       a0 = __builtin_amdgcn_mfma_f32_16x16x32_bf16(wihF[s], uf, a0, 0, 0, 0);
        }
        return a0 + a1;
    };

    arrive_flag(iflags, bid);
    f32x4 gih = ugemm(0);          // t=0 input GEMM hides in the init barrier
    wait_flag(iflags);

    float c = 0.f;
    f32x4 gnext = gih;
    int n = 1;                      // barrier index; counter target = 16*n

    for (int t = 0; t < TT; ++t) {
        #pragma unroll 1
        for (int pass = 0; pass < 2; ++pass, ++n) {
            const int bufR = (t * 2 + pass) & 1;
            float xc = 0.f;
            if (pass) xc = AT_LOAD(&xhat[t * BB + bc]);  // pass-1 scalar feedback

            // recurrent GEMM: prefetch all B-fragments (sc1 -> LLC), then MFMA
            u64 ha[16], hb[16];
            {
                const int rb = bufR ? rbB : rbA;
                #pragma unroll
                for (int s = 0; s < 16; ++s) {
                    ha[s] = AT_LOAD(&h64[rb + s * 128]);
                    hb[s] = AT_LOAD(&h64[rb + s * 128 + 1]);
                }
            }
            f32x4 acc0 = gih;
            f32x4 acc1 = (f32x4){0.f, 0.f, 0.f, 0.f};
            #pragma unroll
            for (int s = 0; s < 16; ++s) {
                union { u64 q[2]; bf16x8 v; } cvt;
                cvt.q[0] = ha[s]; cvt.q[1] = hb[s];
                if (s & 1) acc1 = __builtin_amdgcn_mfma_f32_16x16x32_bf16(whhF[s], cvt.v, acc1, 0, 0, 0);
                else       acc0 = __builtin_amdgcn_mfma_f32_16x16x32_bf16(whhF[s], cvt.v, acc0, 0, 0, 0);
            }
            f32x4 acc = acc0 + acc1;

            // D-layout -> per-cell gates via wave-private LDS
            float4 gw; gw.x = acc[0]; gw.y = acc[1]; gw.z = acc[2]; gw.w = acc[3];
            *(float4*)&gbuf[wid][l16][quad * 4] = gw;
            __syncthreads();
            float gI = gbuf[wid][l16][ 0 + quad] + biasv[0] + xc * rsv[0];
            float gF = gbuf[wid][l16][ 4 + quad] + biasv[1] + xc * rsv[1];
            float gG = gbuf[wid][l16][ 8 + quad] + biasv[2] + xc * rsv[2];
            float gO = gbuf[wid][l16][12 + quad] + biasv[3] + xc * rsv[3];

            float ig = sigm(gI), fg = sigm(gF), gg = tanh_fast(gG), og = sigm(gO);
            c = fg * c + ig * gg;
            float h = og * tanh_fast(c);

            // publish h: pack 2 bf16 (quad pair) -> one u32 sc1 store into buf 1-bufR
            float hp = __shfl_xor(h, 16);
            if (dir == 1 && kc == (HH - 1))
                AT_STORE(&xhat[pass * (TT * BB) + t * BB + bc], h);  // fp32 feedback/output
            if (!(quad & 1)) {
                unsigned lo = (unsigned)__builtin_bit_cast(unsigned short, (__bf16)h);
                unsigned hi = (unsigned)__builtin_bit_cast(unsigned short, (__bf16)hp);
                AT_STORE(&hfrag32[bufR ? ws32_0 : ws32_1], lo | (hi << 16));
            }

            arrive_cnt(gcnt, bid);
            if (pass == 1 && t + 1 < TT)
                gnext = ugemm(t + 1);     // next timestep's input GEMM hides here
            wait_cnt(gcnt, 16 * n);
        }
        gih = gnext;
    }
}

__global__ void epilogue(const float* __restrict__ u, const float* __restrict__ xhat,
                         float* __restrict__ out)
{
    const int i = blockIdx.x * blockDim.x + threadIdx.x;   // over float4 groups
    const float4 uv = ((const float4*)u)[i];
    const int bt = i >> 7;             // 128 float4 per (b,t)
    const int t = bt & (TT - 1);
    const int b = bt >> 10;
    const float s = 0.5f * (xhat[t * BB + b] + xhat[TT * BB + t * BB + b]);
    float4 o;
    o.x = 1.5f * uv.x + s;
    o.y = 1.5f * uv.y + s;
    o.z = 1.5f * uv.z + s;
    o.w = 1.5f * uv.w + s;
    ((float4*)out)[i] = o;
}

extern "C" void kernel_launch(void* const* d_in, const int* in_sizes, int n_in,
                              void* d_out, int out_size, void* d_ws, size_t ws_size,
                              hipStream_t stream) {
    const float* u     = (const float*)d_in[0];
    const float* wih_f = (const float*)d_in[1];
    const float* whh_f = (const float*)d_in[2];
    const float* bih_f = (const float*)d_in[3];
    const float* bhh_f = (const float*)d_in[4];
    const float* wih_b = (const float*)d_in[5];
    const float* whh_b = (const float*)d_in[6];
    const float* bih_b = (const float*)d_in[7];
    const float* bhh_b = (const float*)d_in[8];

    char* ws = (char*)d_ws;
    unsigned short* hfrag = (unsigned short*)(ws + HFRAG_OFF);
    float* xhat           = (float*)(ws + XHAT_OFF);
    int* iflags           = (int*)(ws + IFLAG_OFF);
    int* gcnt             = (int*)(ws + GCNT_OFF);

    lstm_persistent<<<NBLK, 256, 0, stream>>>(
        u, wih_f, whh_f, bih_f, bhh_f, wih_b, whh_b, bih_b, bhh_b,
        hfrag, xhat, iflags, gcnt);

    const int n4 = BB * TT * DD / 4;
    epilogue<<<n4 / 256, 256, 0, stream>>>(u, xhat, (float*)d_out);
}